// Round 1
// baseline (963.527 us; speedup 1.0000x reference)
//
#include <hip/hip_runtime.h>
#include <hip/hip_bf16.h>
#include <cmath>

// Problem constants (match reference setup_inputs)
#define BN_EPS 1e-5f
#define SLOPE 0.2f

__device__ __forceinline__ float lrelu(float x) { return x >= 0.f ? x : SLOPE * x; }

// ----------------- CSR build (group edges by dst) -----------------
__global__ void k_count(const int* __restrict__ ei, int E, int n, int* __restrict__ cnt) {
    int g = blockIdx.x * blockDim.x + threadIdx.x;
    int tot = E + n;
    if (g >= tot) return;
    int dst = (g < E) ? ei[E + g] : (g - E);   // self-loop tail
    atomicAdd(&cnt[dst], 1);
}

__global__ void k_scan1(const int* __restrict__ cnt, int* __restrict__ out /*row_ptr+1*/,
                        int* __restrict__ bsums, int n) {
    __shared__ int tmp[256];
    int t = threadIdx.x;
    int g = blockIdx.x * 256 + t;
    tmp[t] = (g < n) ? cnt[g] : 0;
    __syncthreads();
    for (int off = 1; off < 256; off <<= 1) {
        int a = (t >= off) ? tmp[t - off] : 0;
        __syncthreads();
        tmp[t] += a;
        __syncthreads();
    }
    if (g < n) out[g] = tmp[t];               // inclusive scan of this chunk
    if (t == 255) bsums[blockIdx.x] = tmp[255];
}

__global__ void k_scan2(int* __restrict__ bsums, int nb) {  // nb <= 512
    __shared__ int tmp[512];
    int t = threadIdx.x;
    tmp[t] = (t < nb) ? bsums[t] : 0;
    __syncthreads();
    for (int off = 1; off < 512; off <<= 1) {
        int a = (t >= off) ? tmp[t - off] : 0;
        __syncthreads();
        tmp[t] += a;
        __syncthreads();
    }
    if (t < nb) bsums[t] = (t == 0) ? 0 : tmp[t - 1];  // exclusive block offsets
}

__global__ void k_scan3(int* __restrict__ row_ptr, const int* __restrict__ bsums, int n) {
    int g = blockIdx.x * blockDim.x + threadIdx.x;
    if (g == 0) row_ptr[0] = 0;
    if (g < n) row_ptr[g + 1] += bsums[g >> 8];
}

__global__ void k_scatter(const int* __restrict__ ei, int E, int n,
                          const int* __restrict__ row_ptr, int* __restrict__ cur,
                          int* __restrict__ csr) {
    int g = blockIdx.x * blockDim.x + threadIdx.x;
    int tot = E + n;
    if (g >= tot) return;
    int src, dst;
    if (g < E) { src = ei[g]; dst = ei[E + g]; }
    else       { src = g - E; dst = src; }
    int pos = atomicAdd(&cur[dst], 1);
    csr[row_ptr[dst] + pos] = src;
}

// ----------------- GEMM: out[n x CD] = X[n x K] @ W[K x CD] -----------------
// Block: 256 threads, 16 rows. Thread t: row = t>>4, cols [ (t&15)*CPT , +CPT ).
template <int K, int CD, int CPT>
__global__ void k_gemm(const float* __restrict__ X, const float* __restrict__ W,
                       float* __restrict__ out, int n) {
    __shared__ float wl[K * CD];
    __shared__ float xl[16 * K];
    int t = threadIdx.x;
    for (int i = t * 4; i < K * CD; i += 256 * 4)
        *(float4*)&wl[i] = *(const float4*)&W[i];
    int r0 = blockIdx.x * 16;
    for (int i = t * 4; i < 16 * K; i += 256 * 4) {
        int rr = i / K;
        float4 v = make_float4(0.f, 0.f, 0.f, 0.f);
        if (r0 + rr < n) v = *(const float4*)&X[(size_t)(r0 + rr) * K + (i - rr * K)];
        *(float4*)&xl[i] = v;
    }
    __syncthreads();
    int r = t >> 4;
    int c0 = (t & 15) * CPT;
    float acc[CPT] = {};
    const float* xr = &xl[r * K];
    for (int k = 0; k < K; ++k) {
        float xv = xr[k];
        const float* wr = &wl[k * CD + c0];
#pragma unroll
        for (int j4 = 0; j4 < CPT; j4 += 4) {
            float4 w4 = *(const float4*)&wr[j4];
            acc[j4 + 0] += xv * w4.x;
            acc[j4 + 1] += xv * w4.y;
            acc[j4 + 2] += xv * w4.z;
            acc[j4 + 3] += xv * w4.w;
        }
    }
    if (r0 + r < n) {
        float* orow = &out[(size_t)(r0 + r) * CD + c0];
#pragma unroll
        for (int j = 0; j < CPT; ++j) orow[j] = acc[j];
    }
}

// ----------------- attention scores: s = h@a_src, d = h@a_dst (one wave/node) ---
template <int DIM>
__global__ void k_scores(const float* __restrict__ h, const float* __restrict__ as_,
                         const float* __restrict__ ad_, float* __restrict__ s,
                         float* __restrict__ d, int n) {
    int wave = (blockIdx.x * blockDim.x + threadIdx.x) >> 6;
    int lane = threadIdx.x & 63;
    if (wave >= n) return;
    const float* hr = h + (size_t)wave * DIM;
    float ps = 0.f, pd = 0.f;
#pragma unroll
    for (int i = lane; i < DIM; i += 64) {
        float v = hr[i];
        ps += v * as_[i];
        pd += v * ad_[i];
    }
    for (int off = 32; off; off >>= 1) {
        ps += __shfl_xor(ps, off);
        pd += __shfl_xor(pd, off);
    }
    if (lane == 0) { s[wave] = ps; d[wave] = pd; }
}

// ----------------- GAT aggregate (one wave per dst node) -----------------
// Pass 1: segment max of leaky-relu logits. Pass 2: online exp-weighted gather.
template <int DIM>
__global__ void k_aggregate(const float* __restrict__ h, const float* __restrict__ s,
                            const float* __restrict__ d, const int* __restrict__ row_ptr,
                            const int* __restrict__ csr, float* __restrict__ out, int n) {
    int wave = (blockIdx.x * blockDim.x + threadIdx.x) >> 6;
    int lane = threadIdx.x & 63;
    if (wave >= n) return;
    int beg = row_ptr[wave], end = row_ptr[wave + 1];
    float dv = d[wave];
    // pass 1: max logit (lane-strided)
    float m = -INFINITY;
    for (int e = beg + lane; e < end; e += 64) {
        float l = lrelu(s[csr[e]] + dv);
        m = fmaxf(m, l);
    }
    for (int off = 32; off; off >>= 1) m = fmaxf(m, __shfl_xor(m, off));
    // pass 2: serial over edges; lanes parallel over features
    constexpr int FPL = DIM / 64;
    float acc[FPL];
#pragma unroll
    for (int i = 0; i < FPL; ++i) acc[i] = 0.f;
    float denom = 0.f;
    for (int e = beg; e < end; ++e) {
        int srcn = csr[e];
        float w = __expf(lrelu(s[srcn] + dv) - m);
        denom += w;
        const float* hr = h + (size_t)srcn * DIM;
#pragma unroll
        for (int i = 0; i < FPL; ++i) acc[i] += w * hr[lane + i * 64];
    }
    float inv = 1.f / denom;
    float* orow = out + (size_t)wave * DIM;
#pragma unroll
    for (int i = 0; i < FPL; ++i) orow[lane + i * 64] = acc[i] * inv;
}

// ----------------- BatchNorm -----------------
template <int CD>
__global__ void k_bn_stats(const float* __restrict__ x, float* __restrict__ sums, int n) {
    constexpr int RPB = 256 / CD;
    int t = threadIdx.x;
    int c = t & (CD - 1);
    int rl = t / CD;
    float s = 0.f, sq = 0.f;
    for (int r = blockIdx.x * RPB + rl; r < n; r += gridDim.x * RPB) {
        float v = x[(size_t)r * CD + c];
        s += v;
        sq += v * v;
    }
    __shared__ float ls[256], lq[256];
    ls[t] = s; lq[t] = sq;
    __syncthreads();
    if (t < CD) {
#pragma unroll
        for (int j = 1; j < RPB; ++j) { s += ls[t + j * CD]; sq += lq[t + j * CD]; }
        atomicAdd(&sums[c], s);
        atomicAdd(&sums[CD + c], sq);
    }
}

template <int CD>
__global__ void k_bn_apply(const float* __restrict__ x, const float* __restrict__ sums,
                           const float* __restrict__ g, const float* __restrict__ b,
                           float* __restrict__ out, int n) {
    size_t i = (size_t)blockIdx.x * blockDim.x + threadIdx.x;
    size_t tot = (size_t)n * CD;
    if (i >= tot) return;
    int c = (int)(i & (CD - 1));
    float invn = 1.f / (float)n;
    float mu = sums[c] * invn;
    float var = sums[CD + c] * invn - mu * mu;
    float v = (x[i] - mu) * rsqrtf(var + BN_EPS) * g[c] + b[c];
    out[i] = fmaxf(v, 0.f);
}

// ----------------- launch -----------------
extern "C" void kernel_launch(void* const* d_in, const int* in_sizes, int n_in,
                              void* d_out, int out_size, void* d_ws, size_t ws_size,
                              hipStream_t stream) {
    const float* x   = (const float*)d_in[0];
    const int*   ei  = (const int*)  d_in[1];
    const float* W0  = (const float*)d_in[2];
    const float* as0 = (const float*)d_in[3];
    const float* ad0 = (const float*)d_in[4];
    const float* g0  = (const float*)d_in[5];
    const float* b0  = (const float*)d_in[6];
    const float* W1  = (const float*)d_in[7];
    const float* as1 = (const float*)d_in[8];
    const float* ad1 = (const float*)d_in[9];
    const float* g1  = (const float*)d_in[10];
    const float* b1  = (const float*)d_in[11];
    float* out = (float*)d_out;

    const int N_ = in_sizes[0] / 128;  // 100000
    const int E_ = in_sizes[1] / 2;    // 1600000
    const int TOT = E_ + N_;           // edges incl. self-loops

    // ---- workspace layout ----
    float* h0   = (float*)d_ws;               // N*128 (reused as h1 | agg1 later)
    float* agg0 = h0 + (size_t)N_ * 128;      // N*128 (bn0 in-place)
    float* s0   = agg0 + (size_t)N_ * 128;    // N
    float* d0   = s0 + N_;                    // N
    float* bns0 = d0 + N_;                    // 256
    float* bns1 = bns0 + 256;                 // 128
    int* cnt    = (int*)(bns1 + 128);         // N
    int* rowp   = cnt + N_;                   // N+1
    int* bsums  = rowp + N_ + 1;              // <=512
    int* csr    = bsums + 512;                // E+N
    float* h1   = h0;                         // N*64
    float* agg1 = h0 + (size_t)N_ * 64;       // N*64

    const int nbScan = (N_ + 255) / 256;      // 391 (<=512 required)

    // zero counters / stat accumulators
    hipMemsetAsync(cnt, 0, (size_t)N_ * 4, stream);
    hipMemsetAsync(bns0, 0, 256 * 4, stream);
    hipMemsetAsync(bns1, 0, 128 * 4, stream);

    // CSR build
    k_count<<<(TOT + 255) / 256, 256, 0, stream>>>(ei, E_, N_, cnt);
    k_scan1<<<nbScan, 256, 0, stream>>>(cnt, rowp + 1, bsums, N_);
    k_scan2<<<1, 512, 0, stream>>>(bsums, nbScan);
    k_scan3<<<nbScan, 256, 0, stream>>>(rowp, bsums, N_);
    hipMemsetAsync(cnt, 0, (size_t)N_ * 4, stream);
    k_scatter<<<(TOT + 255) / 256, 256, 0, stream>>>(ei, E_, N_, rowp, cnt, csr);

    const int gemmBlocks = (N_ + 15) / 16;
    const int waveBlocks = (N_ + 3) / 4;      // 4 waves/block, 1 wave/node

    // ---- layer 0 ----
    k_gemm<128, 128, 8><<<gemmBlocks, 256, 0, stream>>>(x, W0, h0, N_);
    k_scores<128><<<waveBlocks, 256, 0, stream>>>(h0, as0, ad0, s0, d0, N_);
    k_aggregate<128><<<waveBlocks, 256, 0, stream>>>(h0, s0, d0, rowp, csr, agg0, N_);
    k_bn_stats<128><<<256, 256, 0, stream>>>(agg0, bns0, N_);
    k_bn_apply<128><<<(int)(((size_t)N_ * 128 + 255) / 256), 256, 0, stream>>>(
        agg0, bns0, g0, b0, agg0, N_);

    // ---- layer 1 ----
    k_gemm<128, 64, 4><<<gemmBlocks, 256, 0, stream>>>(agg0, W1, h1, N_);
    k_scores<64><<<waveBlocks, 256, 0, stream>>>(h1, as1, ad1, s0, d0, N_);
    k_aggregate<64><<<waveBlocks, 256, 0, stream>>>(h1, s0, d0, rowp, csr, agg1, N_);
    k_bn_stats<64><<<256, 256, 0, stream>>>(agg1, bns1, N_);
    k_bn_apply<64><<<(int)(((size_t)N_ * 64 + 255) / 256), 256, 0, stream>>>(
        agg1, bns1, g1, b1, out, N_);
}